// Round 3
// baseline (417.996 us; speedup 1.0000x reference)
//
#include <hip/hip_runtime.h>

#define HH 2000
#define WW 1000
#define HWSZ (HH * WW)
#define NEG_INF (-3.0e38f)

// ---- monotone float<->uint encoding for atomicMax on floats ----
__device__ __forceinline__ unsigned fenc(float f) {
    unsigned u = __float_as_uint(f);
    return (u & 0x80000000u) ? ~u : (u | 0x80000000u);
}
__device__ __forceinline__ float fdec(unsigned k) {
    unsigned u = (k & 0x80000000u) ? (k & 0x7fffffffu) : ~k;
    return __uint_as_float(u);
}

__global__ void init_buckets(unsigned* __restrict__ buck, int n) {
    int i = blockIdx.x * blockDim.x + threadIdx.x;
    if (i < n) buck[i] = 0u;  // 0 < enc(x) for every real float x
}

__global__ void decode_buckets(unsigned* __restrict__ buck, int n) {
    int i = blockIdx.x * blockDim.x + threadIdx.x;
    if (i < n) {
        unsigned k = buck[i];
        ((float*)buck)[i] = fdec(k);
    }
}

// Fully-unrolled dense layer + ReLU, one pixel per thread. Weight/bias
// indices are compile-time -> uniform s_load into SGPRs, FMA uses the
// SGPR operand slot. Zero VGPR cost for weights.
template <int C, int O>
__device__ __forceinline__ void layer_relu(const float* __restrict__ w,
                                           const float* __restrict__ b,
                                           const float* __restrict__ x,
                                           float* __restrict__ y) {
#pragma unroll
    for (int o = 0; o < O; ++o) {
        float a = b[o];
#pragma unroll
        for (int c = 0; c < C; ++c) {
            a = fmaf(w[o * C + c], x[c], a);
        }
        y[o] = fmaxf(a, 0.0f);
    }
}

__global__ __launch_bounds__(256) void mlp_max_kernel(
    const float* __restrict__ in,
    const float* __restrict__ w1, const float* __restrict__ b1,
    const float* __restrict__ w2, const float* __restrict__ b2,
    const float* __restrict__ w3, const float* __restrict__ b3,
    const float* __restrict__ w4, const float* __restrict__ b4,
    unsigned* __restrict__ rowbuck, unsigned* __restrict__ colbuck) {
    __shared__ float cred[4][64];

    const int tx = threadIdx.x;           // 0..63 (lane)
    const int ty = threadIdx.y;           // 0..3  (wave id)

    const int col = blockIdx.x * 64 + tx;   // 0..1023 (>=1000 masked)
    const int rb = blockIdx.y * 16;         // block covers rows rb..rb+15
    const bool colok = (col < WW);

    float colmax = NEG_INF;

    for (int kk = 0; kk < 4; ++kk) {
        const int r = rb + kk * 4 + ty;     // wave-uniform row, always < HH
        const int p = colok ? (r * WW + col) : (r * WW);

        float x[36], y[18];
#pragma unroll
        for (int c = 0; c < 9; ++c) {
            x[c] = in[c * HWSZ + p];        // coalesced across lanes
        }

        layer_relu<9, 18>(w1, b1, x, y);    // live: 9 + 18
        layer_relu<18, 36>(w2, b2, y, x);   // live: 18 + 36

        // layer 3 fused with layer 4: never materialize the 36-wide L3 output
        float s = b4[0];
#pragma unroll
        for (int o = 0; o < 36; ++o) {
            float a = b3[o];
#pragma unroll
            for (int c = 0; c < 36; ++c) {
                a = fmaf(w3[o * 36 + c], x[c], a);
            }
            s = fmaf(w4[o], fmaxf(a, 0.0f), s);
        }

        s = colok ? s : NEG_INF;
        colmax = fmaxf(colmax, s);

        // row max: all 64 lanes of this wave share the same row r
        float m = s;
#pragma unroll
        for (int off = 32; off > 0; off >>= 1) {
            m = fmaxf(m, __shfl_xor(m, off, 64));
        }
        if (tx == 0) {
            atomicMax(&rowbuck[r], fenc(m));
        }
    }

    // col max: reduce the 4 waves' per-column maxima through LDS
    cred[ty][tx] = colmax;
    __syncthreads();
    if (ty == 0 && colok) {
        float m = fmaxf(fmaxf(cred[0][tx], cred[1][tx]),
                        fmaxf(cred[2][tx], cred[3][tx]));
        atomicMax(&colbuck[col], fenc(m));
    }
}

extern "C" void kernel_launch(void* const* d_in, const int* in_sizes, int n_in,
                              void* d_out, int out_size, void* d_ws, size_t ws_size,
                              hipStream_t stream) {
    const float* in = (const float*)d_in[0];
    // d_in[1] = T_out (unused), d_in[2] = T_indices (identity, unused)
    const float* w1 = (const float*)d_in[3];
    const float* b1 = (const float*)d_in[4];
    const float* w2 = (const float*)d_in[5];
    const float* b2 = (const float*)d_in[6];
    const float* w3 = (const float*)d_in[7];
    const float* b3 = (const float*)d_in[8];
    const float* w4 = (const float*)d_in[9];
    const float* b4 = (const float*)d_in[10];

    unsigned* buck = (unsigned*)d_out;  // [0,2000) row maxes, [2000,3000) col maxes

    init_buckets<<<(3000 + 255) / 256, 256, 0, stream>>>(buck, 3000);

    dim3 block(64, 4);
    dim3 grid(16, 125);  // 16*64=1024 >= 1000 cols ; 125*16=2000 rows exactly
    mlp_max_kernel<<<grid, block, 0, stream>>>(in, w1, b1, w2, b2, w3, b3, w4, b4,
                                               buck, buck + 2000);

    decode_buckets<<<(3000 + 255) / 256, 256, 0, stream>>>(buck, 3000);
}

// Round 4
// 393.614 us; speedup vs baseline: 1.0619x; 1.0619x over previous
//
#include <hip/hip_runtime.h>

#define HH 2000
#define WW 1000
#define HWSZ (HH * WW)
#define NEG_INF (-3.0e38f)

// ---- monotone float<->uint encoding for atomicMax on floats ----
__device__ __forceinline__ unsigned fenc(float f) {
    unsigned u = __float_as_uint(f);
    return (u & 0x80000000u) ? ~u : (u | 0x80000000u);
}
__device__ __forceinline__ float fdec(unsigned k) {
    unsigned u = (k & 0x80000000u) ? (k & 0x7fffffffu) : ~k;
    return __uint_as_float(u);
}

__global__ void init_buckets(unsigned* __restrict__ buck, int n) {
    int i = blockIdx.x * blockDim.x + threadIdx.x;
    if (i < n) buck[i] = 0u;  // 0 < enc(x) for every real float x
}

__global__ void decode_buckets(unsigned* __restrict__ buck, int n) {
    int i = blockIdx.x * blockDim.x + threadIdx.x;
    if (i < n) {
        unsigned k = buck[i];
        ((float*)buck)[i] = fdec(k);
    }
}

// Fully-unrolled dense layer + ReLU applied to TWO pixels per thread:
// each s_loaded weight feeds 2 FMAs, halving scalar-stream traffic per pixel.
template <int C, int O>
__device__ __forceinline__ void layer_pair_relu(const float* __restrict__ w,
                                                const float* __restrict__ b,
                                                const float* __restrict__ x0,
                                                const float* __restrict__ x1,
                                                float* __restrict__ y0,
                                                float* __restrict__ y1) {
#pragma unroll
    for (int o = 0; o < O; ++o) {
        float a0 = b[o];
        float a1 = a0;
#pragma unroll
        for (int c = 0; c < C; ++c) {
            float wv = w[o * C + c];
            a0 = fmaf(wv, x0[c], a0);
            a1 = fmaf(wv, x1[c], a1);
        }
        y0[o] = fmaxf(a0, 0.0f);
        y1[o] = fmaxf(a1, 0.0f);
    }
}

__global__ __launch_bounds__(256, 2) void mlp_max_kernel(
    const float* __restrict__ in,
    const float* __restrict__ w1, const float* __restrict__ b1,
    const float* __restrict__ w2, const float* __restrict__ b2,
    const float* __restrict__ w3, const float* __restrict__ b3,
    const float* __restrict__ w4, const float* __restrict__ b4,
    unsigned* __restrict__ rowbuck, unsigned* __restrict__ colbuck) {
    __shared__ float cred[4][64];

    const int tx = threadIdx.x;           // 0..63 (lane)
    const int ty = threadIdx.y;           // 0..3  (wave id)

    const int col = blockIdx.x * 64 + tx;   // 0..1023 (>=1000 masked)
    const int rb = blockIdx.y * 16;         // block covers rows rb..rb+15
    const bool colok = (col < WW);

    float colmax = NEG_INF;

#pragma unroll 1
    for (int kk = 0; kk < 2; ++kk) {
        const int r0 = rb + kk * 8 + ty;    // wave-uniform rows, always < HH
        const int r1 = r0 + 4;
        const int p0 = colok ? (r0 * WW + col) : (r0 * WW);
        const int p1 = colok ? (r1 * WW + col) : (r1 * WW);

        float xa0[36], xa1[36], ya0[18], ya1[18];
#pragma unroll
        for (int c = 0; c < 9; ++c) {
            xa0[c] = in[c * HWSZ + p0];     // coalesced across lanes
            xa1[c] = in[c * HWSZ + p1];
        }

        layer_pair_relu<9, 18>(w1, b1, xa0, xa1, ya0, ya1);   // -> 18x2
        layer_pair_relu<18, 36>(w2, b2, ya0, ya1, xa0, xa1);  // -> 36x2

        // layer 3 fused with layer 4: never materialize the 36-wide L3 output
        float s0 = b4[0];
        float s1 = s0;
#pragma unroll
        for (int o = 0; o < 36; ++o) {
            float bo = b3[o];
            float a0 = bo, a1 = bo;
#pragma unroll
            for (int c = 0; c < 36; ++c) {
                float wv = w3[o * 36 + c];
                a0 = fmaf(wv, xa0[c], a0);
                a1 = fmaf(wv, xa1[c], a1);
            }
            float w4o = w4[o];
            s0 = fmaf(w4o, fmaxf(a0, 0.0f), s0);
            s1 = fmaf(w4o, fmaxf(a1, 0.0f), s1);
        }

        s0 = colok ? s0 : NEG_INF;
        s1 = colok ? s1 : NEG_INF;
        colmax = fmaxf(colmax, fmaxf(s0, s1));

        // row max: all 64 lanes of this wave share rows r0, r1
        float m0 = s0, m1 = s1;
#pragma unroll
        for (int off = 32; off > 0; off >>= 1) {
            m0 = fmaxf(m0, __shfl_xor(m0, off, 64));
            m1 = fmaxf(m1, __shfl_xor(m1, off, 64));
        }
        if (tx == 0) {
            atomicMax(&rowbuck[r0], fenc(m0));
            atomicMax(&rowbuck[r1], fenc(m1));
        }
    }

    // col max: reduce the 4 waves' per-column maxima through LDS
    cred[ty][tx] = colmax;
    __syncthreads();
    if (ty == 0 && colok) {
        float m = fmaxf(fmaxf(cred[0][tx], cred[1][tx]),
                        fmaxf(cred[2][tx], cred[3][tx]));
        atomicMax(&colbuck[col], fenc(m));
    }
}

extern "C" void kernel_launch(void* const* d_in, const int* in_sizes, int n_in,
                              void* d_out, int out_size, void* d_ws, size_t ws_size,
                              hipStream_t stream) {
    const float* in = (const float*)d_in[0];
    // d_in[1] = T_out (unused), d_in[2] = T_indices (identity, unused)
    const float* w1 = (const float*)d_in[3];
    const float* b1 = (const float*)d_in[4];
    const float* w2 = (const float*)d_in[5];
    const float* b2 = (const float*)d_in[6];
    const float* w3 = (const float*)d_in[7];
    const float* b3 = (const float*)d_in[8];
    const float* w4 = (const float*)d_in[9];
    const float* b4 = (const float*)d_in[10];

    unsigned* buck = (unsigned*)d_out;  // [0,2000) row maxes, [2000,3000) col maxes

    init_buckets<<<(3000 + 255) / 256, 256, 0, stream>>>(buck, 3000);

    dim3 block(64, 4);
    dim3 grid(16, 125);  // 16*64=1024 >= 1000 cols ; 125*16=2000 rows exactly
    mlp_max_kernel<<<grid, block, 0, stream>>>(in, w1, b1, w2, b2, w3, b3, w4, b4,
                                               buck, buck + 2000);

    decode_buckets<<<(3000 + 255) / 256, 256, 0, stream>>>(buck, 3000);
}